// Round 19
// baseline (316.349 us; speedup 1.0000x reference)
//
#include <hip/hip_runtime.h>
#include <hip/hip_bf16.h>
#include <cstdint>
#include <math.h>

// ---------------------------------------------------------------------------
// GMemLinear: out = (x @ W^T) + bias, W = jax.random.normal(key(seed),[N,K],f64)
// R19: R12's proven quad-buffer BK=32 schedule + staging, MFMA switched to
// 32x32x16 (2495 vs 2075 TF ceiling, 4x fewer instructions). Read-side-only
// change: lane l reads subtile wr*8+mi*2+((l>>4)&1), row l&15, slot
// (ks*2+(l>>5)) ^ (((l&15)>>1)&3)  [inverse of the staged swizzle].
// Operand/C-D maps = R8-verified. Split prefetch: 6 reads/cluster, lgkm(6).
// Pre-kernel = R17.
// ---------------------------------------------------------------------------

typedef __bf16  bf16x8  __attribute__((ext_vector_type(8)));
typedef float   f32x16  __attribute__((ext_vector_type(16)));
typedef unsigned short u16x8 __attribute__((ext_vector_type(8)));

__device__ __forceinline__ unsigned short f2bf_rne(float f) {
  uint32_t x = __float_as_uint(f);
  uint32_t r = (x + 0x7FFFu + ((x >> 16) & 1u)) >> 16;
  return (unsigned short)r;
}

// Threefry-2x32, 20 rounds (Random123 / JAX).
__device__ __forceinline__ void threefry2x32(uint32_t k0, uint32_t k1,
                                             uint32_t x0, uint32_t x1,
                                             uint32_t& o0, uint32_t& o1) {
  uint32_t ks0 = k0, ks1 = k1, ks2 = k0 ^ k1 ^ 0x1BD11BDAu;
  uint32_t ks[3] = {ks0, ks1, ks2};
  x0 += ks0; x1 += ks1;
  const uint32_t rot0[4] = {13u, 15u, 26u, 6u};
  const uint32_t rot1[4] = {17u, 29u, 16u, 24u};
#pragma unroll
  for (int i = 0; i < 5; ++i) {
    const uint32_t* r = (i & 1) ? rot1 : rot0;
#pragma unroll
    for (int j = 0; j < 4; ++j) {
      x0 += x1;
      x1 = (x1 << r[j]) | (x1 >> (32u - r[j]));
      x1 ^= x0;
    }
    x0 += ks[(i + 1) % 3];
    x1 += ks[(i + 2) % 3] + (uint32_t)(i + 1);
  }
  o0 = x0; o1 = x1;
}

// All-f32 normal from the 52-bit mantissa draw (JAX-compatible to ~1e-3).
__device__ __forceinline__ float normal_from_bits_f32(uint64_t m52) {
  const bool pos = (m52 >> 51) & 1;
  uint64_t dmin = pos ? ((1ull << 52) - m52) : m52;
  uint32_t hi = (uint32_t)(dmin >> 27);
  uint32_t lo = (uint32_t)(dmin & 0x7FFFFFFu);
  float oma = fmaf((float)hi, 0x1p-24f, (float)lo * 0x1p-51f);
  oma = fmaxf(oma, 0x1p-53f);
  float au  = 1.0f - oma;
  float u   = pos ? au : -au;
  float opa = 2.0f - oma;
  float t   = oma * opa;
  float wf  = -__logf(t);
  float x;
  if (wf < 15.5f) {
    float w, p;
    if (wf < 5.0f) {
      w = wf - 2.5f;
      p = 2.81022636e-08f;
      p = 3.43273939e-07f + p * w;
      p = -3.5233877e-06f + p * w;
      p = -4.39150654e-06f + p * w;
      p = 0.00021858087f + p * w;
      p = -0.00125372503f + p * w;
      p = -0.00417768164f + p * w;
      p = 0.246640727f + p * w;
      p = 1.50140941f + p * w;
    } else {
      w = sqrtf(wf) - 3.0f;
      p = -0.000200214257f;
      p = 0.000100950558f + p * w;
      p = 0.00134934322f + p * w;
      p = -0.00367342844f + p * w;
      p = 0.00573950773f + p * w;
      p = -0.0076224613f + p * w;
      p = 0.00943887047f + p * w;
      p = 1.00167406f + p * w;
      p = 2.83297682f + p * w;
    }
    x = p * u;
  } else {
    float L = wf + __logf(opa);
    float r = sqrtf(L);
    r = sqrtf(L - __logf(r) - 0.57236494f);
    r = sqrtf(L - __logf(r) - 0.57236494f);
    x = pos ? r : -r;
  }
  return 1.41421356f * x;
}

__device__ __forceinline__ void cast_phase(const float* __restrict__ X,
                                           unsigned short* __restrict__ Y,
                                           int nx, int gid, int gsz) {
  const int n8 = nx >> 3;
  for (int q = gid; q < n8; q += gsz) {
    const float4* p = (const float4*)(X + ((size_t)q << 3));
    float4 a = p[0], b = p[1];
    u16x8 o;
    o[0] = f2bf_rne(a.x); o[1] = f2bf_rne(a.y);
    o[2] = f2bf_rne(a.z); o[3] = f2bf_rne(a.w);
    o[4] = f2bf_rne(b.x); o[5] = f2bf_rne(b.y);
    o[6] = f2bf_rne(b.z); o[7] = f2bf_rne(b.w);
    *(u16x8*)(Y + ((size_t)q << 3)) = o;
  }
}

__device__ __forceinline__ void gen_phase(unsigned short* __restrict__ W,
                                          uint32_t k1, int nw, int gid, int gsz) {
  const uint32_t k0 = 0u;
  const int nq = nw >> 2;
  for (int q = gid; q < nq; q += gsz) {
    ushort4 outv;
    unsigned short tmp[4];
#pragma unroll
    for (int j = 0; j < 4; ++j) {
      uint32_t e = ((uint32_t)q << 2) + (uint32_t)j;
      uint32_t o0, o1;
      threefry2x32(k0, k1, 0u, e, o0, o1);
      uint64_t bits = ((uint64_t)o0 << 32) | (uint64_t)o1;
      tmp[j] = f2bf_rne(normal_from_bits_f32(bits >> 12));
    }
    outv.x = tmp[0]; outv.y = tmp[1]; outv.z = tmp[2]; outv.w = tmp[3];
    *(ushort4*)(W + ((size_t)q << 2)) = outv;
  }
}

__global__ void gen_and_cast(const float* __restrict__ X,
                             unsigned short* __restrict__ Y,
                             unsigned short* __restrict__ W,
                             const int* __restrict__ seedp,
                             int nx, int nw) {
  const int gsz = (int)(gridDim.x * blockDim.x);
  const int gid = (int)(blockIdx.x * blockDim.x + threadIdx.x);
  const uint32_t k1 = (uint32_t)seedp[0];
  if (blockIdx.x & 1) {
    cast_phase(X, Y, nx, gid, gsz);
    gen_phase(W, k1, nw, gid, gsz);
  } else {
    gen_phase(W, k1, nw, gid, gsz);
    cast_phase(X, Y, nx, gid, gsz);
  }
}

// ---------------------------------------------------------------------------
// 256x256 GEMM, BK=32, quad-buffer, 32x32x16 MFMA, split prefetch.
// ---------------------------------------------------------------------------

__device__ __forceinline__ void gload_lds16(const void* g, void* l) {
  __builtin_amdgcn_global_load_lds(
      (const __attribute__((address_space(1))) unsigned int*)g,
      (__attribute__((address_space(3))) unsigned int*)l, 16, 0, 0);
}

__device__ __forceinline__ uint32_t lds_u32(void* p) {
  return (uint32_t)(uintptr_t)(__attribute__((address_space(3))) char*)p;
}

template <int OFF>
__device__ __forceinline__ bf16x8 dsr16(uint32_t a) {
  bf16x8 r;
  asm volatile("ds_read_b128 %0, %1 offset:%2" : "=v"(r) : "v"(a), "i"(OFF));
  return r;
}

__global__ __launch_bounds__(512, 2) void gemm256(
    const unsigned short* __restrict__ A,   // [M][K] bf16
    const unsigned short* __restrict__ B,   // [N][K] bf16
    const float* __restrict__ bias,         // [N]
    float* __restrict__ C,                  // [M][N] f32
    int M, int N, int K) {
  __shared__ __align__(1024) char lds[131072];

  const int nwg = (int)gridDim.x;
  int wg = (int)blockIdx.x;
  wg = (wg & 7) * (nwg >> 3) + (wg >> 3);       // bijective: nwg % 8 == 0
  const int ntn = N >> 8;
  const int tm = wg / ntn, tn = wg - tm * ntn;

  const int tid = (int)threadIdx.x;
  const int w = tid >> 6, l = tid & 63;
  const int wr = w >> 2, wc = w & 3;            // wave grid 2(M) x 4(N)
  const int l15   = l & 15;
  const int lhalf = (l >> 4) & 1;
  const int lhi   = l >> 5;
  const int xsw   = (l15 >> 1) & 3;

  // stage-side (R12 exact): lane l sources global row l>>2, col pre-swizzled
  const int stRow = l >> 2;
  const int stCol = (((l & 3) ^ ((l >> 3) & 3)) << 4);

  const char* Ag = (const char*)A;
  const char* Bg = (const char*)B;
  const long rowA0 = (long)tm * 256;
  const long rowB0 = (long)tn * 256;
  const long Kb = (long)K;

  const uint32_t lds0 = lds_u32(&lds[0]);
  // read bases per k-step ks (slot = ks*2 + lhi, XORed with row swizzle)
  const uint32_t koff0 = (uint32_t)(((0 * 2 + lhi) ^ xsw) << 4);
  const uint32_t koff1 = (uint32_t)(((1 * 2 + lhi) ^ xsw) << 4);
  const uint32_t aRd = lds0 + (uint32_t)(wr * 8192 + lhalf * 1024 + l15 * 64);
  const uint32_t bRd = lds0 + 16384u + (uint32_t)(wc * 4096 + lhalf * 1024 + l15 * 64);
  const uint32_t aB0 = aRd + koff0, aB1 = aRd + koff1;
  const uint32_t bB0 = bRd + koff0, bB1 = bRd + koff1;

#define STAGE_A(kt_, cs_)                                                     \
  _Pragma("unroll")                                                           \
  for (int i_ = 0; i_ < 2; ++i_) {                                            \
    const int u_ = w * 2 + i_;                                                \
    gload_lds16(Ag + 2 * ((rowA0 + u_ * 16 + stRow) * Kb + (long)(kt_) * 32) + stCol, \
                &lds[(cs_) * 32768 + u_ * 1024]);                             \
  }
#define STAGE_B(kt_, cs_)                                                     \
  _Pragma("unroll")                                                           \
  for (int i_ = 0; i_ < 2; ++i_) {                                            \
    const int u_ = w * 2 + i_;                                                \
    gload_lds16(Bg + 2 * ((rowB0 + u_ * 16 + stRow) * Kb + (long)(kt_) * 32) + stCol, \
                &lds[(cs_) * 32768 + 16384 + u_ * 1024]);                     \
  }

  // prefetch cluster ks for buffer cn_: 4 A-frags + 2 B-frags (6 reads)
#define PF_C0(cn_)                                                            \
  {                                                                           \
    const uint32_t aB_ = aB0 + (cn_) * 32768u;                                \
    const uint32_t bB_ = bB0 + (cn_) * 32768u;                                \
    aq[0][0] = dsr16<0>(aB_);    aq[0][1] = dsr16<2048>(aB_);                 \
    aq[0][2] = dsr16<4096>(aB_); aq[0][3] = dsr16<6144>(aB_);                 \
    bq[0][0] = dsr16<0>(bB_);    bq[0][1] = dsr16<2048>(bB_);                 \
  }
#define PF_C1(cn_)                                                            \
  {                                                                           \
    const uint32_t aB_ = aB1 + (cn_) * 32768u;                                \
    const uint32_t bB_ = bB1 + (cn_) * 32768u;                                \
    aq[1][0] = dsr16<0>(aB_);    aq[1][1] = dsr16<2048>(aB_);                 \
    aq[1][2] = dsr16<4096>(aB_); aq[1][3] = dsr16<6144>(aB_);                 \
    bq[1][0] = dsr16<0>(bB_);    bq[1][1] = dsr16<2048>(bB_);                 \
  }

#define MFMAQ(ks_)                                                            \
  _Pragma("unroll")                                                           \
  for (int mi = 0; mi < 4; ++mi)                                              \
    _Pragma("unroll")                                                         \
    for (int nj = 0; nj < 2; ++nj)                                            \
      acc[mi][nj] = __builtin_amdgcn_mfma_f32_32x32x16_bf16(                  \
          aq[ks_][mi], bq[ks_][nj], acc[mi][nj], 0, 0, 0);

#define TILE_BODY(c_, kt_, vm_, st_, pf_)                                     \
  {                                                                           \
    asm volatile("s_waitcnt lgkmcnt(6)" ::: "memory");                        \
    __builtin_amdgcn_sched_barrier(0);                                        \
    __builtin_amdgcn_s_setprio(1);                                            \
    MFMAQ(0)                                                                  \
    __builtin_amdgcn_s_setprio(0);                                            \
    if (pf_) { PF_C0(((c_) + 1) & 3) }                                        \
    if (st_) { STAGE_A((kt_) + 3, ((c_) + 3) & 3) }                           \
    if (pf_) { asm volatile("s_waitcnt lgkmcnt(6)" ::: "memory"); }           \
    else     { asm volatile("s_waitcnt lgkmcnt(0)" ::: "memory"); }           \
    __builtin_amdgcn_sched_barrier(0);                                        \
    __builtin_amdgcn_s_setprio(1);                                            \
    MFMAQ(1)                                                                  \
    __builtin_amdgcn_s_setprio(0);                                            \
    if (pf_) { PF_C1(((c_) + 1) & 3) }                                        \
    if (st_) { STAGE_B((kt_) + 3, ((c_) + 3) & 3) }                           \
    asm volatile("s_waitcnt vmcnt(" #vm_ ")" ::: "memory");                   \
    __builtin_amdgcn_sched_barrier(0);                                        \
    __builtin_amdgcn_s_barrier();                                             \
  }

  f32x16 acc[4][2];
#pragma unroll
  for (int i = 0; i < 4; ++i)
#pragma unroll
    for (int j = 0; j < 2; ++j)
#pragma unroll
      for (int e = 0; e < 16; ++e) acc[i][j][e] = 0.f;

  bf16x8 aq[2][4], bq[2][2];

  const int NTt = K >> 5;   // 128 K-tiles of BK=32

  // prologue: stage tiles 0,1,2; vmcnt(4) retires tiles 0,1; barrier;
  // then tile-0 reads in steady-state order (cluster 0 then cluster 1).
  STAGE_A(0, 0) STAGE_B(0, 0)
  STAGE_A(1, 1) STAGE_B(1, 1)
  STAGE_A(2, 2) STAGE_B(2, 2)
  asm volatile("s_waitcnt vmcnt(4)" ::: "memory");
  __builtin_amdgcn_sched_barrier(0);
  __builtin_amdgcn_s_barrier();
  PF_C0(0)
  PF_C1(0)

  int kt = 0;
  for (; kt + 7 < NTt; kt += 4) {
    TILE_BODY(0, kt,     4, 1, 1)
    TILE_BODY(1, kt + 1, 4, 1, 1)
    TILE_BODY(2, kt + 2, 4, 1, 1)
    TILE_BODY(3, kt + 3, 4, 1, 1)
  }
  // peel: tiles NTt-4 .. NTt-1
  TILE_BODY(0, kt,     4, 1, 1)   // stages tile NTt-1
  TILE_BODY(1, kt + 1, 0, 0, 1)
  TILE_BODY(2, kt + 2, 0, 0, 1)
  TILE_BODY(3, kt + 3, 0, 0, 0)

  // epilogue (R8-verified 32x32 C/D): col = l&31, row = (reg&3)+8*(reg>>2)+4*lhi
#pragma unroll
  for (int nj = 0; nj < 2; ++nj) {
    const int col = tn * 256 + wc * 64 + nj * 32 + (l & 31);
    const float bv = bias[col];
#pragma unroll
    for (int mi = 0; mi < 4; ++mi) {
      const int r0 = tm * 256 + wr * 128 + mi * 32 + (lhi << 2);
      f32x16 v = acc[mi][nj];
#pragma unroll
      for (int reg = 0; reg < 16; ++reg) {
        const int row = r0 + (reg & 3) + 8 * (reg >> 2);
        C[(size_t)row * N + col] = v[reg] + bv;
      }
    }
  }
#undef STAGE_A
#undef STAGE_B
#undef PF_C0
#undef PF_C1
#undef MFMAQ
#undef TILE_BODY
}

// ---------------------------------------------------------------------------
extern "C" void kernel_launch(void* const* d_in, const int* in_sizes, int n_in,
                              void* d_out, int out_size, void* d_ws, size_t ws_size,
                              hipStream_t stream) {
  const float* x    = (const float*)d_in[0];
  const float* bias = (const float*)d_in[1];
  const int*   seed = (const int*)d_in[2];
  float* out = (float*)d_out;

  const int K = 4096;                       // IN_FEATURES
  const int N = in_sizes[1];                // OUT_FEATURES (4096)
  const int M = in_sizes[0] / K;            // BATCH*SEQ (8192)

  unsigned short* W  = (unsigned short*)d_ws;
  unsigned short* Xb = W + (size_t)N * K;

  gen_and_cast<<<2048, 256, 0, stream>>>(x, Xb, W, seed, M * K, N * K);

  dim3 grid((M / 256) * (N / 256));
  gemm256<<<grid, 512, 0, stream>>>((const unsigned short*)Xb,
                                    (const unsigned short*)W,
                                    bias, out, M, N, K);
}

// Round 20
// 300.099 us; speedup vs baseline: 1.0541x; 1.0541x over previous
//
#include <hip/hip_runtime.h>
#include <hip/hip_bf16.h>
#include <cstdint>
#include <math.h>

// ---------------------------------------------------------------------------
// GMemLinear: out = (x @ W^T) + bias, W = jax.random.normal(key(seed),[N,K],f64)
// R20 (final) = R17 exact: best-expectation measured configuration.
//   GEMM: R12 quad-buffer BK=32, split cross-tile register prefetch,
//         counted lgkm(4)/vmcnt(4), 1 barrier/tile, proven stage/read swizzle
//         (231 us, MfmaUtil 56-58%, 0 bank conflicts, VGPR 128).
//   Pre:  unified grid-stride gen+cast, parity-ordered phases, all-f32 gen
//         with integer-exact tail.
// Session notes: 7 GEMM schedule variants bracket this structure at 52-59%
// MfmaUtil; 32x32 MFMA raised util to 59% but added 2.5e7 bank conflicts
// (net flat); 8-phase BK=64 ledger ran correct but slower (240us). The
// documented path past ~60% is the full HK-style co-design (not reproduced
// here in three attempts).
// ---------------------------------------------------------------------------

typedef __bf16  bf16x8 __attribute__((ext_vector_type(8)));
typedef float   f32x4  __attribute__((ext_vector_type(4)));
typedef unsigned short u16x8 __attribute__((ext_vector_type(8)));

__device__ __forceinline__ unsigned short f2bf_rne(float f) {
  uint32_t x = __float_as_uint(f);
  uint32_t r = (x + 0x7FFFu + ((x >> 16) & 1u)) >> 16;
  return (unsigned short)r;
}

// Threefry-2x32, 20 rounds (Random123 / JAX).
__device__ __forceinline__ void threefry2x32(uint32_t k0, uint32_t k1,
                                             uint32_t x0, uint32_t x1,
                                             uint32_t& o0, uint32_t& o1) {
  uint32_t ks0 = k0, ks1 = k1, ks2 = k0 ^ k1 ^ 0x1BD11BDAu;
  uint32_t ks[3] = {ks0, ks1, ks2};
  x0 += ks0; x1 += ks1;
  const uint32_t rot0[4] = {13u, 15u, 26u, 6u};
  const uint32_t rot1[4] = {17u, 29u, 16u, 24u};
#pragma unroll
  for (int i = 0; i < 5; ++i) {
    const uint32_t* r = (i & 1) ? rot1 : rot0;
#pragma unroll
    for (int j = 0; j < 4; ++j) {
      x0 += x1;
      x1 = (x1 << r[j]) | (x1 >> (32u - r[j]));
      x1 ^= x0;
    }
    x0 += ks[(i + 1) % 3];
    x1 += ks[(i + 2) % 3] + (uint32_t)(i + 1);
  }
  o0 = x0; o1 = x1;
}

// All-f32 normal from the 52-bit mantissa draw (JAX-compatible to ~1e-3).
__device__ __forceinline__ float normal_from_bits_f32(uint64_t m52) {
  const bool pos = (m52 >> 51) & 1;
  uint64_t dmin = pos ? ((1ull << 52) - m52) : m52;
  uint32_t hi = (uint32_t)(dmin >> 27);
  uint32_t lo = (uint32_t)(dmin & 0x7FFFFFFu);
  float oma = fmaf((float)hi, 0x1p-24f, (float)lo * 0x1p-51f);
  oma = fmaxf(oma, 0x1p-53f);
  float au  = 1.0f - oma;
  float u   = pos ? au : -au;
  float opa = 2.0f - oma;
  float t   = oma * opa;
  float wf  = -__logf(t);
  float x;
  if (wf < 15.5f) {
    float w, p;
    if (wf < 5.0f) {
      w = wf - 2.5f;
      p = 2.81022636e-08f;
      p = 3.43273939e-07f + p * w;
      p = -3.5233877e-06f + p * w;
      p = -4.39150654e-06f + p * w;
      p = 0.00021858087f + p * w;
      p = -0.00125372503f + p * w;
      p = -0.00417768164f + p * w;
      p = 0.246640727f + p * w;
      p = 1.50140941f + p * w;
    } else {
      w = sqrtf(wf) - 3.0f;
      p = -0.000200214257f;
      p = 0.000100950558f + p * w;
      p = 0.00134934322f + p * w;
      p = -0.00367342844f + p * w;
      p = 0.00573950773f + p * w;
      p = -0.0076224613f + p * w;
      p = 0.00943887047f + p * w;
      p = 1.00167406f + p * w;
      p = 2.83297682f + p * w;
    }
    x = p * u;
  } else {
    float L = wf + __logf(opa);
    float r = sqrtf(L);
    r = sqrtf(L - __logf(r) - 0.57236494f);
    r = sqrtf(L - __logf(r) - 0.57236494f);
    x = pos ? r : -r;
  }
  return 1.41421356f * x;
}

// ---------------------------------------------------------------------------
// Pre-kernel phases; each block runs both, order by block parity so the
// memory-bound cast and VALU-bound gen overlap chip-wide.
// ---------------------------------------------------------------------------
__device__ __forceinline__ void cast_phase(const float* __restrict__ X,
                                           unsigned short* __restrict__ Y,
                                           int nx, int gid, int gsz) {
  const int n8 = nx >> 3;
  for (int q = gid; q < n8; q += gsz) {
    const float4* p = (const float4*)(X + ((size_t)q << 3));
    float4 a = p[0], b = p[1];
    u16x8 o;
    o[0] = f2bf_rne(a.x); o[1] = f2bf_rne(a.y);
    o[2] = f2bf_rne(a.z); o[3] = f2bf_rne(a.w);
    o[4] = f2bf_rne(b.x); o[5] = f2bf_rne(b.y);
    o[6] = f2bf_rne(b.z); o[7] = f2bf_rne(b.w);
    *(u16x8*)(Y + ((size_t)q << 3)) = o;
  }
}

__device__ __forceinline__ void gen_phase(unsigned short* __restrict__ W,
                                          uint32_t k1, int nw, int gid, int gsz) {
  const uint32_t k0 = 0u;
  const int nq = nw >> 2;
  for (int q = gid; q < nq; q += gsz) {
    ushort4 outv;
    unsigned short tmp[4];
#pragma unroll
    for (int j = 0; j < 4; ++j) {
      uint32_t e = ((uint32_t)q << 2) + (uint32_t)j;
      uint32_t o0, o1;
      threefry2x32(k0, k1, 0u, e, o0, o1);
      uint64_t bits = ((uint64_t)o0 << 32) | (uint64_t)o1;
      tmp[j] = f2bf_rne(normal_from_bits_f32(bits >> 12));
    }
    outv.x = tmp[0]; outv.y = tmp[1]; outv.z = tmp[2]; outv.w = tmp[3];
    *(ushort4*)(W + ((size_t)q << 2)) = outv;
  }
}

__global__ void gen_and_cast(const float* __restrict__ X,
                             unsigned short* __restrict__ Y,
                             unsigned short* __restrict__ W,
                             const int* __restrict__ seedp,
                             int nx, int nw) {
  const int gsz = (int)(gridDim.x * blockDim.x);
  const int gid = (int)(blockIdx.x * blockDim.x + threadIdx.x);
  const uint32_t k1 = (uint32_t)seedp[0];
  if (blockIdx.x & 1) {
    cast_phase(X, Y, nx, gid, gsz);
    gen_phase(W, k1, nw, gid, gsz);
  } else {
    gen_phase(W, k1, nw, gid, gsz);
    cast_phase(X, Y, nx, gid, gsz);
  }
}

// ---------------------------------------------------------------------------
// 256x256 GEMM, BK=32, quad-buffer, interleaved split prefetch (R12 exact).
// ---------------------------------------------------------------------------

__device__ __forceinline__ void gload_lds16(const void* g, void* l) {
  __builtin_amdgcn_global_load_lds(
      (const __attribute__((address_space(1))) unsigned int*)g,
      (__attribute__((address_space(3))) unsigned int*)l, 16, 0, 0);
}

__device__ __forceinline__ uint32_t lds_u32(void* p) {
  return (uint32_t)(uintptr_t)(__attribute__((address_space(3))) char*)p;
}

template <int OFF>
__device__ __forceinline__ bf16x8 dsr16(uint32_t a) {
  bf16x8 r;
  asm volatile("ds_read_b128 %0, %1 offset:%2" : "=v"(r) : "v"(a), "i"(OFF));
  return r;
}

__global__ __launch_bounds__(512, 2) void gemm256(
    const unsigned short* __restrict__ A,   // [M][K] bf16
    const unsigned short* __restrict__ B,   // [N][K] bf16
    const float* __restrict__ bias,         // [N]
    float* __restrict__ C,                  // [M][N] f32
    int M, int N, int K) {
  __shared__ __align__(1024) char lds[131072];

  const int nwg = (int)gridDim.x;
  int wg = (int)blockIdx.x;
  wg = (wg & 7) * (nwg >> 3) + (wg >> 3);       // bijective: nwg % 8 == 0
  const int ntn = N >> 8;
  const int tm = wg / ntn, tn = wg - tm * ntn;

  const int tid = (int)threadIdx.x;
  const int w = tid >> 6, l = tid & 63;
  const int wr = w >> 2, wc = w & 3;            // wave grid 2(M) x 4(N)
  const int l15 = l & 15;

  // read-side swizzled lane offset within a 1KiB (16row x 64B) subtile
  int laneRd = (l15 << 6) | ((l >> 4) << 4);
  laneRd ^= ((l15 >> 1) & 3) << 4;
  // stage-side: lane l sources global row l>>2, col-slot pre-inverse-swizzled
  const int stRow = l >> 2;
  const int stCol = (((l & 3) ^ ((l >> 3) & 3)) << 4);

  const char* Ag = (const char*)A;
  const char* Bg = (const char*)B;
  const long rowA0 = (long)tm * 256;
  const long rowB0 = (long)tn * 256;
  const long Kb = (long)K;

  const uint32_t lds0  = lds_u32(&lds[0]);
  const uint32_t aBase = lds0 + (uint32_t)(wr * 8192 + laneRd);
  const uint32_t bBase = lds0 + 16384u + (uint32_t)(wc * 4096 + laneRd);

#define STAGE_A(kt_, cs_)                                                     \
  _Pragma("unroll")                                                           \
  for (int i_ = 0; i_ < 2; ++i_) {                                            \
    const int u_ = w * 2 + i_;                                                \
    gload_lds16(Ag + 2 * ((rowA0 + u_ * 16 + stRow) * Kb + (long)(kt_) * 32) + stCol, \
                &lds[(cs_) * 32768 + u_ * 1024]);                             \
  }
#define STAGE_B(kt_, cs_)                                                     \
  _Pragma("unroll")                                                           \
  for (int i_ = 0; i_ < 2; ++i_) {                                            \
    const int u_ = w * 2 + i_;                                                \
    gload_lds16(Bg + 2 * ((rowB0 + u_ * 16 + stRow) * Kb + (long)(kt_) * 32) + stCol, \
                &lds[(cs_) * 32768 + 16384 + u_ * 1024]);                     \
  }

#define PF_A03(cn_)                                                           \
  {                                                                           \
    const uint32_t aB = aBase + (cn_) * 32768u;                               \
    aq[0] = dsr16<0>(aB);    aq[1] = dsr16<1024>(aB);                         \
    aq[2] = dsr16<2048>(aB); aq[3] = dsr16<3072>(aB);                         \
  }
#define PF_REST(cn_)                                                          \
  {                                                                           \
    const uint32_t aB = aBase + (cn_) * 32768u;                               \
    const uint32_t bB = bBase + (cn_) * 32768u;                               \
    bq[0] = dsr16<0>(bB);    bq[1] = dsr16<1024>(bB);                         \
    bq[2] = dsr16<2048>(bB); bq[3] = dsr16<3072>(bB);                         \
    aq[4] = dsr16<4096>(aB); aq[5] = dsr16<5120>(aB);                         \
    aq[6] = dsr16<6144>(aB); aq[7] = dsr16<7168>(aB);                         \
  }

#define MFMA16(base_)                                                         \
  _Pragma("unroll")                                                           \
  for (int mi = 0; mi < 4; ++mi)                                              \
    _Pragma("unroll")                                                         \
    for (int ni = 0; ni < 4; ++ni)                                            \
      acc[(base_) + mi][ni] = __builtin_amdgcn_mfma_f32_16x16x32_bf16(        \
          aq[(base_) + mi], bq[ni], acc[(base_) + mi][ni], 0, 0, 0);

#define TILE_BODY(c_, kt_, vm_, st_, pf_)                                     \
  {                                                                           \
    asm volatile("s_waitcnt lgkmcnt(4)" ::: "memory");                        \
    __builtin_amdgcn_sched_barrier(0);                                        \
    __builtin_amdgcn_s_setprio(1);                                            \
    MFMA16(0)                                                                 \
    __builtin_amdgcn_s_setprio(0);                                            \
    if (pf_) { PF_A03(((c_) + 1) & 3) }                                       \
    if (st_) { STAGE_A((kt_) + 3, ((c_) + 3) & 3) }                           \
    if (pf_) { asm volatile("s_waitcnt lgkmcnt(4)" ::: "memory"); }           \
    else     { asm volatile("s_waitcnt lgkmcnt(0)" ::: "memory"); }           \
    __builtin_amdgcn_sched_barrier(0);                                        \
    __builtin_amdgcn_s_setprio(1);                                            \
    MFMA16(4)                                                                 \
    __builtin_amdgcn_s_setprio(0);                                            \
    if (pf_) { PF_REST(((c_) + 1) & 3) }                                      \
    if (st_) { STAGE_B((kt_) + 3, ((c_) + 3) & 3) }                           \
    asm volatile("s_waitcnt vmcnt(" #vm_ ")" ::: "memory");                   \
    __builtin_amdgcn_sched_barrier(0);                                        \
    __builtin_amdgcn_s_barrier();                                             \
  }

  f32x4 acc[8][4];
#pragma unroll
  for (int i = 0; i < 8; ++i)
#pragma unroll
    for (int j = 0; j < 4; ++j) acc[i][j] = (f32x4){0.f, 0.f, 0.f, 0.f};

  bf16x8 aq[8], bq[4];

  const int NTt = K >> 5;   // 128 K-tiles of BK=32

  STAGE_A(0, 0) STAGE_B(0, 0)
  STAGE_A(1, 1) STAGE_B(1, 1)
  STAGE_A(2, 2) STAGE_B(2, 2)
  asm volatile("s_waitcnt vmcnt(4)" ::: "memory");
  __builtin_amdgcn_sched_barrier(0);
  __builtin_amdgcn_s_barrier();
  PF_A03(0)
  PF_REST(0)

  int kt = 0;
  for (; kt + 7 < NTt; kt += 4) {
    TILE_BODY(0, kt,     4, 1, 1)
    TILE_BODY(1, kt + 1, 4, 1, 1)
    TILE_BODY(2, kt + 2, 4, 1, 1)
    TILE_BODY(3, kt + 3, 4, 1, 1)
  }
  TILE_BODY(0, kt,     4, 1, 1)   // stages tile NTt-1
  TILE_BODY(1, kt + 1, 0, 0, 1)
  TILE_BODY(2, kt + 2, 0, 0, 1)
  TILE_BODY(3, kt + 3, 0, 0, 0)

  // epilogue: C/D layout col = lane&15, row = (lane>>4)*4 + j
#pragma unroll
  for (int ni = 0; ni < 4; ++ni) {
    const int col = tn * 256 + wc * 64 + ni * 16 + l15;
    const float bv = bias[col];
#pragma unroll
    for (int mi = 0; mi < 8; ++mi) {
      const int r0 = tm * 256 + wr * 128 + mi * 16 + ((l >> 4) << 2);
      f32x4 v = acc[mi][ni];
#pragma unroll
      for (int j = 0; j < 4; ++j)
        C[(size_t)(r0 + j) * N + col] = v[j] + bv;
    }
  }
#undef STAGE_A
#undef STAGE_B
#undef PF_A03
#undef PF_REST
#undef MFMA16
#undef TILE_BODY
}

// ---------------------------------------------------------------------------
extern "C" void kernel_launch(void* const* d_in, const int* in_sizes, int n_in,
                              void* d_out, int out_size, void* d_ws, size_t ws_size,
                              hipStream_t stream) {
  const float* x    = (const float*)d_in[0];
  const float* bias = (const float*)d_in[1];
  const int*   seed = (const int*)d_in[2];
  float* out = (float*)d_out;

  const int K = 4096;                       // IN_FEATURES
  const int N = in_sizes[1];                // OUT_FEATURES (4096)
  const int M = in_sizes[0] / K;            // BATCH*SEQ (8192)

  unsigned short* W  = (unsigned short*)d_ws;
  unsigned short* Xb = W + (size_t)N * K;

  gen_and_cast<<<2048, 256, 0, stream>>>(x, Xb, W, seed, M * K, N * K);

  dim3 grid((M / 256) * (N / 256));
  gemm256<<<grid, 512, 0, stream>>>((const unsigned short*)Xb,
                                    (const unsigned short*)W,
                                    bias, out, M, N, K);
}